// Round 13
// baseline (599.080 us; speedup 1.0000x reference)
//
#include <hip/hip_runtime.h>
#include <math.h>

#define NZc     64
#define EMBEDc  256
#define DMc     256
#define NHc     16
#define HDc     16
#define DFFc    1024
#define NLc     6
#define E1Dc    32
#define PDIMc   64
#define PMAXLc  24
#define NBINSc  49
#define NB      8
#define Lc      512
#define NTOK    (NB * Lc)        // 4096
#define UMDIM   (EMBEDc + E1Dc)  // 288

typedef __attribute__((ext_vector_type(4))) float f4;
typedef __attribute__((ext_vector_type(8))) short bf8;   // 8 bf16 in 4 VGPRs

#define MFMA(a, b, c) __builtin_amdgcn_mfma_f32_16x16x32_bf16((a), (b), (c), 0, 0, 0)

__device__ __forceinline__ short f2bf(float f) {
    unsigned u = __float_as_uint(f);
    u += 0x7FFFu + ((u >> 16) & 1u);   // round-to-nearest-even
    return (short)(u >> 16);
}
__device__ __forceinline__ float bf2f(short s) {
    return __uint_as_float(((unsigned)(unsigned short)s) << 16);
}

// ---------------------------------------------------------------------------
// preamble: weight conversions (x8 vectorized) + bias bins + e_aa + z^T.
__global__ void k_pre(const float* __restrict__ Wq, const float* __restrict__ Wk,
                      const float* __restrict__ Wv, const float* __restrict__ Wo,
                      const float* __restrict__ Wf1, const float* __restrict__ Wf2,
                      const float* __restrict__ exw1, const float* __restrict__ exw2,
                      const float* __restrict__ ow1,
                      const float* __restrict__ pos_emb, const float* __restrict__ W2d,
                      const float* __restrict__ b2d, const float* __restrict__ x,
                      const float* __restrict__ aa_emb, const float* __restrict__ z,
                      short* __restrict__ wqkv_hi, short* __restrict__ wqkv_lo,
                      short* __restrict__ wo_hi, short* __restrict__ wo_lo,
                      short* __restrict__ wf1_hi, short* __restrict__ wf1_lo,
                      short* __restrict__ wf2_hi, short* __restrict__ wf2_lo,
                      short* __restrict__ wex1_hi, short* __restrict__ wex1_lo,
                      short* __restrict__ wex2_hi, short* __restrict__ wex2_lo,
                      short* __restrict__ wo1_hi, short* __restrict__ wo1_lo,
                      float* __restrict__ bb,
                      short* __restrict__ umhi, short* __restrict__ umlo,
                      short* __restrict__ zth, short* __restrict__ ztl) {
    int stride = gridDim.x * blockDim.x;
    int tid = blockIdx.x * blockDim.x + threadIdx.x;
#define CVT(src, hi, lo, per_layer, dstride, doff, scale, total)               \
    for (int i = tid; i < (total) / 8; i += stride) {                          \
        int ib = i * 8;                                                        \
        int ll = ib / (per_layer), rels = ib - ll * (per_layer);               \
        size_t di = (size_t)ll * (dstride) + (doff) + rels;                    \
        f4 v0 = *(const f4*)(src + ib);                                        \
        f4 v1 = *(const f4*)(src + ib + 4);                                    \
        bf8 hv, lv;                                                            \
        _Pragma("unroll")                                                      \
        for (int q = 0; q < 4; ++q) {                                          \
            float v = v0[q] * (scale);                                         \
            short hh = f2bf(v);                                                \
            hv[q] = hh;                                                        \
            lv[q] = f2bf(v - bf2f(hh));                                        \
        }                                                                      \
        _Pragma("unroll")                                                      \
        for (int q = 0; q < 4; ++q) {                                          \
            float v = v1[q] * (scale);                                         \
            short hh = f2bf(v);                                                \
            hv[q + 4] = hh;                                                    \
            lv[q + 4] = f2bf(v - bf2f(hh));                                    \
        }                                                                      \
        *(bf8*)(hi + di) = hv;                                                 \
        *(bf8*)(lo + di) = lv;                                                 \
    }
    CVT(Wq,  wqkv_hi, wqkv_lo, 65536, 196608, 0,      0.0625f, 393216);
    CVT(Wk,  wqkv_hi, wqkv_lo, 65536, 196608, 65536,  1.f,     393216);
    CVT(Wv,  wqkv_hi, wqkv_lo, 65536, 196608, 131072, 1.f,     393216);
    CVT(Wo,  wo_hi,  wo_lo,  65536,  65536,  0, 1.f, 393216);
    CVT(Wf1, wf1_hi, wf1_lo, 294912, 294912, 0, 1.f, 1769472);
    CVT(Wf2, wf2_hi, wf2_lo, 262144, 262144, 0, 1.f, 1572864);
    CVT(exw1, wex1_hi, wex1_lo, 16384, 16384, 0, 1.f, 16384);
    CVT(exw2, wex2_hi, wex2_lo, 65536, 65536, 0, 1.f, 65536);
    CVT(ow1,  wo1_hi,  wo1_lo,  65536, 65536, 0, 1.f, 65536);
#undef CVT
    for (int idx = tid; idx < NLc * NHc * NBINSc; idx += stride) {
        int bin = idx % NBINSc;
        int tmp = idx / NBINSc;
        int hh = tmp % NHc, l = tmp / NHc;
        float s = b2d[l * NHc + hh];
        const float* pe = pos_emb + bin * PDIMc;
        const float* w  = W2d + (l * NHc + hh) * PDIMc;
        for (int p = 0; p < PDIMc; ++p) s += pe[p] * w[p];
        bb[idx] = s;
    }
    for (int tok = tid; tok < NTOK; tok += stride) {
        int n = tok / Lc, l = tok % Lc;
        const float* xp = x + (size_t)n * 20 * Lc + l;
        float best = xp[0];
        int bi = 0;
        for (int c = 1; c < 20; ++c) {
            float v = xp[c * Lc];
            if (v > best) { best = v; bi = c; }
        }
        const float* e = aa_emb + bi * E1Dc;
        bf8 hv, lv;
        for (int c8 = 0; c8 < E1Dc / 8; ++c8) {
#pragma unroll
            for (int q = 0; q < 8; ++q) {
                float v = e[c8 * 8 + q];
                short hh = f2bf(v);
                hv[q] = hh;
                lv[q] = f2bf(v - bf2f(hh));
            }
            *(bf8*)(umhi + (size_t)tok * UMDIM + EMBEDc + c8 * 8) = hv;
            *(bf8*)(umlo + (size_t)tok * UMDIM + EMBEDc + c8 * 8) = lv;
        }
    }
    for (int tok = tid; tok < NTOK; tok += stride) {
        int n = tok >> 9, l = tok & 511;
        bf8 hv, lv;
        for (int c8 = 0; c8 < NZc / 8; ++c8) {
#pragma unroll
            for (int q = 0; q < 8; ++q) {
                float v = z[((size_t)n * NZc + c8 * 8 + q) * Lc + l];
                short hh = f2bf(v);
                hv[q] = hh;
                lv[q] = f2bf(v - bf2f(hh));
            }
            *(bf8*)(zth + (size_t)tok * NZc + c8 * 8) = hv;
            *(bf8*)(ztl + (size_t)tok * NZc + c8 * 8) = lv;
        }
    }
}

// ---------------------------------------------------------------------------
// LDS-staged MFMA GEMM (unchanged from round 12)
template <int EPI, int MF, int SKSHIFT, int BK>
__global__ __launch_bounds__(256) void k_gemm3(
    const short* __restrict__ Ahi, const short* __restrict__ Alo, int lda,
    const short* __restrict__ Bhi, const short* __restrict__ Blo, int ldb,
    int K, float* __restrict__ outf, int ldo, short* __restrict__ ohi,
    short* __restrict__ olo, int ldh, const float* __restrict__ bias,
    int gx, int gypx) {
    constexpr int PAD = BK + 8;
    __shared__ __align__(16) short Ah[MF * 64][PAD];
    __shared__ __align__(16) short Al[MF * 64][PAD];
    __shared__ __align__(16) short Bh[64][PAD];
    __shared__ __align__(16) short Bl[64][PAD];

    int bid = blockIdx.x;
    int koff = 0;
    if (SKSHIFT) {
        int kh = bid >> SKSHIFT;
        bid &= (1 << SKSHIFT) - 1;
        koff = kh * K;
        outf += (size_t)kh * NTOK * EMBEDc;
    }
    int xcd = bid & 7, j = bid >> 3;
    int bx = j % gx, by = xcd * gypx + j / gx;

    int t = threadIdx.x;
    int w = t >> 6, l = t & 63, lr = l & 15, lk = l >> 4;
    int m0 = by * (MF * 64);
    int n0 = bx * 64;

    constexpr int TPR = BK / 8;
    constexpr int RP  = 256 / TPR;
    constexpr int AP  = MF * 64 / RP;
    constexpr int BP  = 64 / RP;
    int srow = t / TPR, scol = (t % TPR) * 8;

    const short* pa  = Ahi + (size_t)(m0 + srow) * lda + koff + scol;
    const short* pal = Alo + (size_t)(m0 + srow) * lda + koff + scol;
    const short* pb  = Bhi + (size_t)(n0 + srow) * ldb + koff + scol;
    const short* pbl = Blo + (size_t)(n0 + srow) * ldb + koff + scol;

    bf8 ra[AP], rla[AP], rb[BP], rlb[BP];
#pragma unroll
    for (int p = 0; p < AP; ++p) {
        ra[p]  = *(const bf8*)(pa  + (size_t)p * RP * lda);
        rla[p] = *(const bf8*)(pal + (size_t)p * RP * lda);
    }
#pragma unroll
    for (int p = 0; p < BP; ++p) {
        rb[p]  = *(const bf8*)(pb  + (size_t)p * RP * ldb);
        rlb[p] = *(const bf8*)(pbl + (size_t)p * RP * ldb);
    }

    f4 acc[MF][4];
#pragma unroll
    for (int mf = 0; mf < MF; ++mf)
#pragma unroll
        for (int nf = 0; nf < 4; ++nf) acc[mf][nf] = (f4){0.f, 0.f, 0.f, 0.f};

    for (int ks = 0; ks < K; ks += BK) {
        __syncthreads();
#pragma unroll
        for (int p = 0; p < AP; ++p) {
            *(bf8*)&Ah[p * RP + srow][scol] = ra[p];
            *(bf8*)&Al[p * RP + srow][scol] = rla[p];
        }
#pragma unroll
        for (int p = 0; p < BP; ++p) {
            *(bf8*)&Bh[p * RP + srow][scol] = rb[p];
            *(bf8*)&Bl[p * RP + srow][scol] = rlb[p];
        }
        __syncthreads();
        if (ks + BK < K) {
#pragma unroll
            for (int p = 0; p < AP; ++p) {
                ra[p]  = *(const bf8*)(pa  + (size_t)p * RP * lda + ks + BK);
                rla[p] = *(const bf8*)(pal + (size_t)p * RP * lda + ks + BK);
            }
#pragma unroll
            for (int p = 0; p < BP; ++p) {
                rb[p]  = *(const bf8*)(pb  + (size_t)p * RP * ldb + ks + BK);
                rlb[p] = *(const bf8*)(pbl + (size_t)p * RP * ldb + ks + BK);
            }
        }
#pragma unroll
        for (int kc = 0; kc < BK / 32; ++kc) {
            bf8 bhf[4], blf[4];
#pragma unroll
            for (int nf = 0; nf < 4; ++nf) {
                bhf[nf] = *(const bf8*)&Bh[nf * 16 + lr][kc * 32 + lk * 8];
                blf[nf] = *(const bf8*)&Bl[nf * 16 + lr][kc * 32 + lk * 8];
            }
#pragma unroll
            for (int mf = 0; mf < MF; ++mf) {
                bf8 ah = *(const bf8*)&Ah[w * MF * 16 + mf * 16 + lr][kc * 32 + lk * 8];
                bf8 al = *(const bf8*)&Al[w * MF * 16 + mf * 16 + lr][kc * 32 + lk * 8];
#pragma unroll
                for (int nf = 0; nf < 4; ++nf) {
                    acc[mf][nf] = MFMA(ah, bhf[nf], acc[mf][nf]);
                    acc[mf][nf] = MFMA(ah, blf[nf], acc[mf][nf]);
                    acc[mf][nf] = MFMA(al, bhf[nf], acc[mf][nf]);
                }
            }
        }
    }

#pragma unroll
    for (int mf = 0; mf < MF; ++mf) {
#pragma unroll
        for (int nf = 0; nf < 4; ++nf) {
            int n = n0 + nf * 16 + lr;
            int mbase = m0 + w * MF * 16 + mf * 16 + lk * 4;
            if (EPI == 0) {
#pragma unroll
                for (int r = 0; r < 4; ++r)
                    outf[(size_t)(mbase + r) * ldo + n] = acc[mf][nf][r];
            } else if (EPI == 1) {
                float bv = bias[n];
#pragma unroll
                for (int r = 0; r < 4; ++r) {
                    float y = fmaxf(acc[mf][nf][r] + bv, 0.f);
                    short hv = f2bf(y);
                    size_t oi = (size_t)(mbase + r) * ldh + n;
                    ohi[oi] = hv;
                    olo[oi] = f2bf(y - bf2f(hv));
                }
            } else if (EPI == 2) {
#pragma unroll
                for (int r = 0; r < 4; ++r) {
                    float y = acc[mf][nf][r];
                    short hv = f2bf(y);
                    size_t oi = (size_t)(mbase + r) * ldh + n;
                    ohi[oi] = hv;
                    olo[oi] = f2bf(y - bf2f(hv));
                }
            } else {
                float bv = bias[n];
#pragma unroll
                for (int r = 0; r < 4; ++r) {
                    float y = acc[mf][nf][r] + bv;
                    outf[(size_t)(mbase + r) * ldo + n] = y;
                    short hv = f2bf(y);
                    size_t oi = (size_t)(mbase + r) * ldh + n;
                    ohi[oi] = hv;
                    olo[oi] = f2bf(y - bf2f(hv));
                }
            }
        }
    }
}

// ---------------------------------------------------------------------------
// MFMA flash attention: 256 threads (4 waves), wave = dual 16-q chains (32 q),
// block = 128 q-rows; K/V staged in two 256-key halves (36.6 KB LDS) ->
// 4 blocks/CU = 16 waves/CU with 2x per-wave ILP.
__global__ __launch_bounds__(256, 4) void k_attn(const short* __restrict__ qh,
                                                 const short* __restrict__ ql,
                                                 const float* __restrict__ bb,
                                                 short* __restrict__ ohi,
                                                 short* __restrict__ olo) {
    int bx = blockIdx.x;
    int qt = bx >> 7;            // 0..3; blocks sharing (n,head) same XCD
    int head = bx & 15;
    int n = (bx >> 4) & 7;
    int t = threadIdx.x;
    int w = t >> 6, l = t & 63;
    int lq = l & 15, lk = l >> 4;

    __shared__ __align__(16) short khl[256][40];   // [key][hi0-15|lo16-31|pad]
    __shared__ __align__(16) short vth[16][264];   // V^T hi: [d][key 0..255]
    __shared__ __align__(16) short vtl[16][264];   // V^T lo
    __shared__ float biasr[64];

    if (t < NBINSc) biasr[t] = bb[head * NBINSc + t];
    float bL = bb[head * NBINSc];
    float bR = bb[head * NBINSc + 48];

    size_t base = (size_t)n * Lc * 768 + head * 16;

    int qg = qt * 128 + w * 32 + lq;             // chain0 q; chain1 = +16
    size_t qrow = ((size_t)n * Lc + qg) * 768 + head * 16;
    bf8 B1a = *(const bf8*)(qh + qrow + (lk & 1) * 8);
    bf8 B1b = *(const bf8*)(qh + qrow + 16 * 768 + (lk & 1) * 8);
    bf8 B2a, B2b;
    if (lk < 2) {
        B2a = *(const bf8*)(ql + qrow + lk * 8);
        B2b = *(const bf8*)(ql + qrow + 16 * 768 + lk * 8);
    } else {
#pragma unroll
        for (int i = 0; i < 8; ++i) { B2a[i] = 0; B2b[i] = 0; }
    }

    f4 acc0 = (f4){0.f, 0.f, 0.f, 0.f};
    f4 acc1 = (f4){0.f, 0.f, 0.f, 0.f};
    float m0 = -1e30f, m1 = -1e30f, ls0 = 0.f, ls1 = 0.f;
    int rel0 = lk * 4 - qg;      // chain0 rel of s[0]; += 16 per tile

    for (int half = 0; half < 2; ++half) {
        __syncthreads();          // previous half fully consumed
        // stage K half (256 keys), 4 iters
        for (int u = t; u < 1024; u += 256) {
            int key = u >> 2, seg = u & 3;
            const short* src = (seg < 2 ? qh : ql) + base + 256
                             + (size_t)(half * 256 + key) * 768 + (seg & 1) * 8;
            *(bf8*)&khl[key][seg * 8] = *(const bf8*)src;
        }
        // stage V half transposed, pair-packed b32 writes (2 items/thread)
        for (int v = t; v < 512; v += 256) {
            int u = v & 127;
            int dhalf = (v >> 7) & 1;
            int hl = (v >> 8) & 1;
            int gkey = half * 256 + u * 2;
            const short* vs = (hl ? ql : qh) + base + 512 + (size_t)gkey * 768 + dhalf * 8;
            bf8 A = *(const bf8*)vs;
            bf8 B = *(const bf8*)(vs + 768);
            unsigned* vw = (unsigned*)(hl ? &vtl[0][0] : &vth[0][0]);  // stride 132 words
#pragma unroll
            for (int i = 0; i < 8; ++i)
                vw[(dhalf * 8 + i) * 132 + u] =
                    (unsigned)(unsigned short)A[i] | ((unsigned)(unsigned short)B[i] << 16);
        }
        __syncthreads();

        for (int kt = 0; kt < 16; ++kt, rel0 += 16) {
            bf8 A1 = *(const bf8*)&khl[kt * 16 + lq][lk * 8];
            f4 s0 = (f4){0.f, 0.f, 0.f, 0.f};
            f4 s1 = (f4){0.f, 0.f, 0.f, 0.f};
            __builtin_amdgcn_s_setprio(1);
            s0 = MFMA(A1, B1a, s0);
            s0 = MFMA(A1, B2a, s0);
            s1 = MFMA(A1, B1b, s1);
            s1 = MFMA(A1, B2b, s1);
            __builtin_amdgcn_s_setprio(0);
            if (rel0 >= PMAXLc) {
                s0[0] += bR; s0[1] += bR; s0[2] += bR; s0[3] += bR;
            } else if (rel0 + 3 <= -PMAXLc) {
                s0[0] += bL; s0[1] += bL; s0[2] += bL; s0[3] += bL;
            } else {
#pragma unroll
                for (int r = 0; r < 4; ++r) {
                    int rel = rel0 + r;
                    rel = rel < -PMAXLc ? -PMAXLc : (rel > PMAXLc ? PMAXLc : rel);
                    s0[r] += biasr[rel + PMAXLc];
                }
            }
            int rel1 = rel0 - 16;
            if (rel1 >= PMAXLc) {
                s1[0] += bR; s1[1] += bR; s1[2] += bR; s1[3] += bR;
            } else if (rel1 + 3 <= -PMAXLc) {
                s1[0] += bL; s1[1] += bL; s1[2] += bL; s1[3] += bL;
            } else {
#pragma unroll
                for (int r = 0; r < 4; ++r) {
                    int rel = rel1 + r;
                    rel = rel < -PMAXLc ? -PMAXLc : (rel > PMAXLc ? PMAXLc : rel);
                    s1[r] += biasr[rel + PMAXLc];
                }
            }
            float mt0 = fmaxf(fmaxf(s0[0], s0[1]), fmaxf(s0[2], s0[3]));
            float mt1 = fmaxf(fmaxf(s1[0], s1[1]), fmaxf(s1[2], s1[3]));
            mt0 = fmaxf(mt0, __shfl_xor(mt0, 16));
            mt0 = fmaxf(mt0, __shfl_xor(mt0, 32));
            mt1 = fmaxf(mt1, __shfl_xor(mt1, 16));
            mt1 = fmaxf(mt1, __shfl_xor(mt1, 32));
            if (__any((mt0 > m0 + 8.0f) || (mt1 > m1 + 8.0f))) {
                float mn0 = fmaxf(m0, mt0), a0 = __expf(m0 - mn0);
                float mn1 = fmaxf(m1, mt1), a1 = __expf(m1 - mn1);
                m0 = mn0; m1 = mn1;
                ls0 *= a0; ls1 *= a1;
#pragma unroll
                for (int r = 0; r < 4; ++r) {
                    acc0[r] *= __shfl(a0, lk * 4 + r);
                    acc1[r] *= __shfl(a1, lk * 4 + r);
                }
            }
            f4 p0, p1;
#pragma unroll
            for (int r = 0; r < 4; ++r) {
                p0[r] = __expf(s0[r] - m0);
                p1[r] = __expf(s1[r] - m1);
            }
            ls0 += p0[0] + p0[1] + p0[2] + p0[3];
            ls1 += p1[0] + p1[1] + p1[2] + p1[3];
            int src0 = (lk & 1) * 32 + lq;
            int src1 = src0 + 16;
            float g0[8], g1[8];
#pragma unroll
            for (int jj = 0; jj < 4; ++jj) {
                g0[jj]     = __shfl(p0[jj], src0);
                g0[jj + 4] = __shfl(p0[jj], src1);
                g1[jj]     = __shfl(p1[jj], src0);
                g1[jj + 4] = __shfl(p1[jj], src1);
            }
            bf8 PA0, PA1;
            if (lk < 2) {
#pragma unroll
                for (int jj = 0; jj < 8; ++jj) {
                    PA0[jj] = (short)(__float_as_uint(g0[jj]) >> 16);
                    PA1[jj] = (short)(__float_as_uint(g1[jj]) >> 16);
                }
            } else {
#pragma unroll
                for (int jj = 0; jj < 8; ++jj) {
                    unsigned hu0 = __float_as_uint(g0[jj]) & 0xFFFF0000u;
                    unsigned hu1 = __float_as_uint(g1[jj]) & 0xFFFF0000u;
                    PA0[jj] = (short)(__float_as_uint(g0[jj] - __uint_as_float(hu0)) >> 16);
                    PA1[jj] = (short)(__float_as_uint(g1[jj] - __uint_as_float(hu1)) >> 16);
                }
            }
            bf8 VB1 = *(const bf8*)&vth[lq][kt * 16 + (lk & 1) * 8];
            bf8 VB2;
            if (lk < 2) VB2 = *(const bf8*)&vtl[lq][kt * 16 + lk * 8];
            else {
#pragma unroll
                for (int i = 0; i < 8; ++i) VB2[i] = 0;
            }
            __builtin_amdgcn_s_setprio(1);
            acc0 = MFMA(PA0, VB1, acc0);
            acc0 = MFMA(PA0, VB2, acc0);
            acc1 = MFMA(PA1, VB1, acc1);
            acc1 = MFMA(PA1, VB2, acc1);
            __builtin_amdgcn_s_setprio(0);
        }
    }

    float lr0 = ls0 + __shfl_xor(ls0, 16);
    lr0 += __shfl_xor(lr0, 32);
    float lr1 = ls1 + __shfl_xor(ls1, 16);
    lr1 += __shfl_xor(lr1, 32);
    float inv0 = 1.0f / lr0;
    float inv1 = 1.0f / lr1;
#pragma unroll
    for (int r = 0; r < 4; ++r) {
        float iq0 = __shfl(inv0, lk * 4 + r);
        float iq1 = __shfl(inv1, lk * 4 + r);
        float y0 = acc0[r] * iq0;
        float y1 = acc1[r] * iq1;
        int qo = qt * 128 + w * 32 + lk * 4 + r;
        size_t oi0 = ((size_t)n * Lc + qo) * DMc + head * 16 + lq;
        size_t oi1 = oi0 + (size_t)16 * DMc;
        unsigned hu0 = __float_as_uint(y0) & 0xFFFF0000u;
        unsigned hu1 = __float_as_uint(y1) & 0xFFFF0000u;
        ohi[oi0] = (short)(hu0 >> 16);
        olo[oi0] = (short)(__float_as_uint(y0 - __uint_as_float(hu0)) >> 16);
        ohi[oi1] = (short)(hu1 >> 16);
        olo[oi1] = (short)(__float_as_uint(y1 - __uint_as_float(hu1)) >> 16);
    }
}

// ---------------------------------------------------------------------------
// LN over h + s2a + s2b + sbias, fully f4-vectorized.
__global__ __launch_bounds__(256) void k_ln(const float* __restrict__ s2a,
                                            const float* __restrict__ s2b,
                                            const float* __restrict__ sbias,
                                            const float* __restrict__ g,
                                            const float* __restrict__ bta,
                                            float* __restrict__ h,
                                            short* __restrict__ umhi,
                                            short* __restrict__ umlo) {
    int t = threadIdx.x;
    int tl = t >> 5, j = t & 31;
    size_t gtok = (size_t)blockIdx.x * 8 + tl;
    int d0 = j * 8;
    size_t off = gtok * EMBEDc + d0;
    f4 h0 = *(const f4*)(h + off);
    f4 h1 = *(const f4*)(h + off + 4);
    f4 a0 = *(const f4*)(s2a + off);
    f4 a1 = *(const f4*)(s2a + off + 4);
    f4 b0 = *(const f4*)(s2b + off);
    f4 b1 = *(const f4*)(s2b + off + 4);
    f4 sb0 = *(const f4*)(sbias + d0);
    f4 sb1 = *(const f4*)(sbias + d0 + 4);
    f4 v0 = h0 + a0 + b0 + sb0;
    f4 v1 = h1 + a1 + b1 + sb1;
    float sum = v0[0] + v0[1] + v0[2] + v0[3] + v1[0] + v1[1] + v1[2] + v1[3];
    float ssq = v0[0]*v0[0] + v0[1]*v0[1] + v0[2]*v0[2] + v0[3]*v0[3]
              + v1[0]*v1[0] + v1[1]*v1[1] + v1[2]*v1[2] + v1[3]*v1[3];
#pragma unroll
    for (int off5 = 16; off5; off5 >>= 1) {
        sum += __shfl_xor(sum, off5, 32);
        ssq += __shfl_xor(ssq, off5, 32);
    }
    float mean = sum * (1.f / EMBEDc);
    float var = ssq * (1.f / EMBEDc) - mean * mean;
    float inv = rsqrtf(var + 1e-5f);
    f4 g0 = *(const f4*)(g + d0);
    f4 g1 = *(const f4*)(g + d0 + 4);
    f4 t0 = *(const f4*)(bta + d0);
    f4 t1 = *(const f4*)(bta + d0 + 4);
    f4 y0, y1;
    bf8 hv, lv;
#pragma unroll
    for (int q = 0; q < 4; ++q) {
        float y = (v0[q] - mean) * inv * g0[q] + t0[q];
        y0[q] = y;
        short hh = f2bf(y);
        hv[q] = hh;
        lv[q] = f2bf(y - bf2f(hh));
    }
#pragma unroll
    for (int q = 0; q < 4; ++q) {
        float y = (v1[q] - mean) * inv * g1[q] + t1[q];
        y1[q] = y;
        short hh = f2bf(y);
        hv[q + 4] = hh;
        lv[q + 4] = f2bf(y - bf2f(hh));
    }
    *(f4*)(h + off) = y0;
    *(f4*)(h + off + 4) = y1;
    *(bf8*)(umhi + gtok * UMDIM + d0) = hv;
    *(bf8*)(umlo + gtok * UMDIM + d0) = lv;
}

// ---------------------------------------------------------------------------
__global__ __launch_bounds__(256) void k_r(const short* __restrict__ fh,
                                           const short* __restrict__ fl,
                                           const float* __restrict__ w2,
                                           const float* __restrict__ b2,
                                           float* __restrict__ r) {
    __shared__ float w[3][EMBEDc];
    int t = threadIdx.x;
    for (int u = t; u < 3 * EMBEDc; u += 256) w[u >> 8][u & 255] = w2[u];
    __syncthreads();
    int tok = blockIdx.x * 64 + (t >> 2), o = t & 3;
    if (o < 3) {
        const short* ph = fh + (size_t)tok * EMBEDc;
        const short* pl = fl + (size_t)tok * EMBEDc;
        float s = b2[o];
        for (int c8 = 0; c8 < EMBEDc / 8; ++c8) {
            bf8 vh = *(const bf8*)(ph + c8 * 8);
            bf8 vl = *(const bf8*)(pl + c8 * 8);
#pragma unroll
            for (int j = 0; j < 8; ++j)
                s += (bf2f(vh[j]) + bf2f(vl[j])) * w[o][c8 * 8 + j];
        }
        r[(size_t)tok * 3 + o] = s;
    }
}

// ---------------------------------------------------------------------------
__global__ __launch_bounds__(256) void k_dmap(const float* __restrict__ r,
                                              float* __restrict__ d) {
    int b = blockIdx.x;
    int n = b / Lc;
    float xi = r[(size_t)b * 3], yi = r[(size_t)b * 3 + 1], zi = r[(size_t)b * 3 + 2];
    const float* rn = r + (size_t)n * Lc * 3;
    for (int j = threadIdx.x; j < Lc; j += 256) {
        float dx = xi - rn[j * 3];
        float dy = yi - rn[j * 3 + 1];
        float dz = zi - rn[j * 3 + 2];
        d[(size_t)b * Lc + j] = sqrtf(dx * dx + dy * dy + dz * dz + 1e-12f);
    }
}

// ---------------------------------------------------------------------------
extern "C" void kernel_launch(void* const* d_in, const int* in_sizes, int n_in,
                              void* d_out, int out_size, void* d_ws, size_t ws_size,
                              hipStream_t stream) {
    const float* z       = (const float*)d_in[0];
    const float* x       = (const float*)d_in[1];
    const float* pos_emb = (const float*)d_in[2];
    const float* aa_emb  = (const float*)d_in[3];
    const float* ex_w1   = (const float*)d_in[4];
    const float* ex_b1   = (const float*)d_in[5];
    const float* ex_w2   = (const float*)d_in[6];
    const float* ex_b2   = (const float*)d_in[7];
    const float* Wq      = (const float*)d_in[8];
    const float* Wk      = (const float*)d_in[9];
    const float* Wv      = (const float*)d_in[10];
    const float* Wo      = (const float*)d_in[11];
    const float* bo      = (const float*)d_in[12];
    const float* W2d     = (const float*)d_in[13];
    const float* b2d     = (const float*)d_in[14];
    const float* Wf1     = (const float*)d_in[15];
    const float* bf1     = (const float*)d_in[16];
    const float* Wf2     = (const float*)d_in[17];
    const float* bf2     = (const float*)d_in[18];
    const float* ln1_g   = (const float*)d_in[19];
    const float* ln1_b   = (const float*)d_in[20];
    const float* ln2_g   = (const float*)d_in[21];
    const float* ln2_b   = (const float*)d_in[22];
    const float* o_w1    = (const float*)d_in[23];
    const float* o_b1    = (const float*)d_in[24];
    const float* o_w2    = (const float*)d_in[25];
    const float* o_b2    = (const float*)d_in[26];

    float* h    = (float*)d_ws;                    // 4096*256
    float* s2a  = h + (size_t)NTOK * EMBEDc;
    float* s2b  = s2a + (size_t)NTOK * EMBEDc;
    float* bbuf = s2b + (size_t)NTOK * EMBEDc;     // pad 8192
    float* r    = bbuf + 8192;                     // pad 16384
    short* qkvh = (short*)(r + 16384);             // 4096*768
    short* qkvl = qkvh + (size_t)NTOK * 768;
    short* um_hi = qkvl + (size_t)NTOK * 768;      // 4096*288
    short* um_lo = um_hi + (size_t)NTOK * UMDIM;
    short* o_hi  = um_lo + (size_t)NTOK * UMDIM;   // 4096*256
    short* o_lo  = o_hi + (size_t)NTOK * EMBEDc;
    short* f1_hi = o_lo + (size_t)NTOK * EMBEDc;   // 4096*1024
    short* f1_lo = f1_hi + (size_t)NTOK * DFFc;
    short* wqkv_hi = f1_lo + (size_t)NTOK * DFFc;  // 6*768*256
    short* wqkv_lo = wqkv_hi + (size_t)NLc * 768 * EMBEDc;
    short* wo_hi   = wqkv_lo + (size_t)NLc * 768 * EMBEDc;   // 6*256*256
    short* wo_lo   = wo_hi + (size_t)NLc * EMBEDc * DMc;
    short* wf1_hi  = wo_lo + (size_t)NLc * EMBEDc * DMc;     // 6*1024*288
    short* wf1_lo  = wf1_hi + (size_t)NLc * DFFc * UMDIM;
    short* wf2_hi  = wf1_lo + (size_t)NLc * DFFc * UMDIM;    // 6*256*1024
    short* wf2_lo  = wf2_hi + (size_t)NLc * EMBEDc * DFFc;
    short* wex1_hi = wf2_lo + (size_t)NLc * EMBEDc * DFFc;   // 256*64
    short* wex1_lo = wex1_hi + EMBEDc * NZc;
    short* wex2_hi = wex1_lo + EMBEDc * NZc;                 // 256*256
    short* wex2_lo = wex2_hi + EMBEDc * EMBEDc;
    short* wo1_hi  = wex2_lo + EMBEDc * EMBEDc;              // 256*256
    short* wo1_lo  = wo1_hi + EMBEDc * EMBEDc;
    // zt aliases the o buffer (only used in preamble, before k_attn writes o)
    short* zt_hi = o_hi;
    short* zt_lo = o_lo;

    k_pre<<<1024, 256, 0, stream>>>(Wq, Wk, Wv, Wo, Wf1, Wf2, ex_w1, ex_w2, o_w1,
                                    pos_emb, W2d, b2d, x, aa_emb, z,
                                    wqkv_hi, wqkv_lo, wo_hi, wo_lo,
                                    wf1_hi, wf1_lo, wf2_hi, wf2_lo,
                                    wex1_hi, wex1_lo, wex2_hi, wex2_lo,
                                    wo1_hi, wo1_lo, bbuf, um_hi, um_lo,
                                    zt_hi, zt_lo);

    // embed: relu GEMM -> GEMM (fp32 h + bf16 um)
    k_gemm3<1, 1, 0, 64><<<256, 256, 0, stream>>>(
        zt_hi, zt_lo, NZc, wex1_hi, wex1_lo, NZc, NZc,
        nullptr, 0, f1_hi, f1_lo, EMBEDc, ex_b1, 4, 8);
    k_gemm3<3, 1, 0, 64><<<256, 256, 0, stream>>>(
        f1_hi, f1_lo, EMBEDc, wex2_hi, wex2_lo, EMBEDc, EMBEDc,
        h, EMBEDc, um_hi, um_lo, UMDIM, ex_b2, 4, 8);

    for (int l = 0; l < NLc; ++l) {
        k_gemm3<2, 2, 0, 64><<<384, 256, 0, stream>>>(
            um_hi, um_lo, UMDIM,
            wqkv_hi + (size_t)l * 768 * EMBEDc, wqkv_lo + (size_t)l * 768 * EMBEDc, EMBEDc,
            EMBEDc, nullptr, 0, qkvh, qkvl, 768, nullptr, 12, 4);
        k_attn<<<NB * NHc * 4, 256, 0, stream>>>(qkvh, qkvl, bbuf + (size_t)l * NHc * NBINSc, o_hi, o_lo);
        k_gemm3<0, 1, 8, 64><<<512, 256, 0, stream>>>(
            o_hi, o_lo, EMBEDc,
            wo_hi + (size_t)l * EMBEDc * DMc, wo_lo + (size_t)l * EMBEDc * DMc, DMc,
            128, s2a, EMBEDc, nullptr, nullptr, 0, nullptr, 4, 8);
        k_ln<<<NTOK / 8, 256, 0, stream>>>(s2a, s2b, bo + (size_t)l * EMBEDc,
                                           ln1_g + (size_t)l * EMBEDc, ln1_b + (size_t)l * EMBEDc,
                                           h, um_hi, um_lo);
        k_gemm3<1, 2, 0, 32><<<512, 256, 0, stream>>>(
            um_hi, um_lo, UMDIM,
            wf1_hi + (size_t)l * DFFc * UMDIM, wf1_lo + (size_t)l * DFFc * UMDIM, UMDIM,
            UMDIM, nullptr, 0, f1_hi, f1_lo, DFFc, bf1 + (size_t)l * DFFc, 16, 4);
        k_gemm3<0, 1, 8, 64><<<512, 256, 0, stream>>>(
            f1_hi, f1_lo, DFFc,
            wf2_hi + (size_t)l * EMBEDc * DFFc, wf2_lo + (size_t)l * EMBEDc * DFFc, DFFc,
            512, s2a, EMBEDc, nullptr, nullptr, 0, nullptr, 4, 8);
        k_ln<<<NTOK / 8, 256, 0, stream>>>(s2a, s2b, bf2 + (size_t)l * EMBEDc,
                                           ln2_g + (size_t)l * EMBEDc, ln2_b + (size_t)l * EMBEDc,
                                           h, um_hi, um_lo);
    }

    // final: f = relu(um @ o_w1^T + o_b1) (um cols 0..255 hold h in bf16)
    k_gemm3<1, 1, 0, 64><<<256, 256, 0, stream>>>(
        um_hi, um_lo, UMDIM, wo1_hi, wo1_lo, EMBEDc, EMBEDc,
        nullptr, 0, f1_hi, f1_lo, EMBEDc, o_b1, 4, 8);
    k_r<<<NTOK / 64, 256, 0, stream>>>(f1_hi, f1_lo, o_w2, o_b2, r);
    k_dmap<<<NB * Lc, 256, 0, stream>>>(r, (float*)d_out);
}